// Round 1
// baseline (3032.622 us; speedup 1.0000x reference)
//
#include <hip/hip_runtime.h>
#include <cmath>

namespace {
constexpr int B_  = 2;
constexpr int S_  = 1024;
constexpr int H_  = 512;
constexpr int NH_ = 8;
constexpr int HD_ = 64;
constexpr int I_  = 512;
constexpr int K_  = 65536;
constexpr int M_  = B_ * S_;   // 2048
}

// ---------------------------------------------------------------------------
// Generic fp32 GEMM, B-transposed layout: C[m,n] = act(sum_k A[row(m),k] * W[n,k])
// row(m) = gidx[m] (gather) or m. Optional sigmoid epilogue, optional bias vec.
// Tile 64x64, 256 threads, K-chunk 16. All dims assumed multiples of 64/16.
// ---------------------------------------------------------------------------
template<bool SIG, bool GATH, bool BVEC>
__global__ __launch_bounds__(256) void bikv_gemm_bt(
    const float* __restrict__ A, const float* __restrict__ W,
    float* __restrict__ C, const int* __restrict__ gidx,
    const float* __restrict__ bvec, int N, int Kd,
    long sA, long sW, long sC)
{
  A += (long)blockIdx.z * sA;
  W += (long)blockIdx.z * sW;
  C += (long)blockIdx.z * sC;
  __shared__ float As[64][17];   // +1 pad breaks bank conflicts
  __shared__ float Ws[64][17];
  const int t  = threadIdx.x;
  const int m0 = blockIdx.x * 64;
  const int n0 = blockIdx.y * 64;
  const int ty = t >> 4, tx = t & 15;
  const int lr = t >> 2, lc = (t & 3) << 2;
  long arow;
  if (GATH) arow = (long)gidx[m0 + lr] * Kd;
  else      arow = (long)(m0 + lr) * Kd;
  const long wrow = (long)(n0 + lr) * Kd;
  float acc[4][4] = {};
  for (int kk = 0; kk < Kd; kk += 16) {
    __syncthreads();
    const float4 av = *(const float4*)(A + arow + kk + lc);
    const float4 wv = *(const float4*)(W + wrow + kk + lc);
    As[lr][lc+0]=av.x; As[lr][lc+1]=av.y; As[lr][lc+2]=av.z; As[lr][lc+3]=av.w;
    Ws[lr][lc+0]=wv.x; Ws[lr][lc+1]=wv.y; Ws[lr][lc+2]=wv.z; Ws[lr][lc+3]=wv.w;
    __syncthreads();
#pragma unroll
    for (int c = 0; c < 16; ++c) {
      float a[4], b[4];
#pragma unroll
      for (int i = 0; i < 4; ++i) a[i] = As[ty + 16*i][c];
#pragma unroll
      for (int j = 0; j < 4; ++j) b[j] = Ws[tx + 16*j][c];
#pragma unroll
      for (int i = 0; i < 4; ++i)
#pragma unroll
        for (int j = 0; j < 4; ++j) acc[i][j] = fmaf(a[i], b[j], acc[i][j]);
    }
  }
#pragma unroll
  for (int i = 0; i < 4; ++i) {
    const long m = m0 + ty + 16*i;
#pragma unroll
    for (int j = 0; j < 4; ++j) {
      const int n = n0 + tx + 16*j;
      float v = acc[i][j];
      if (BVEC) v += bvec[n];
      if (SIG)  v = 1.0f / (1.0f + expf(-v));
      C[m * N + n] = v;
    }
  }
}

// ---------------------------------------------------------------------------
// sim = idx . tab^T fused with running argmax per row. Never materializes
// the [2048 x 65536] sim matrix. Packed key = (monotone_f32 << 32) | ~col:
// atomicMax => max value, ties broken toward LOWEST col (numpy argmax).
// ---------------------------------------------------------------------------
__global__ __launch_bounds__(256) void bikv_sim_argmax(
    const float* __restrict__ A,      // idx [M_, I_]
    const float* __restrict__ Tb,     // indices_tab [K_, I_]
    unsigned long long* __restrict__ amax)
{
  __shared__ float As[64][17];
  __shared__ float Ws[64][17];
  const int t  = threadIdx.x;
  const int m0 = blockIdx.x * 64;
  const int n0 = blockIdx.y * 64;
  const int ty = t >> 4, tx = t & 15;
  const int lr = t >> 2, lc = (t & 3) << 2;
  const long arow = (long)(m0 + lr) * I_;
  const long wrow = (long)(n0 + lr) * I_;
  float acc[4][4] = {};
  for (int kk = 0; kk < I_; kk += 16) {
    __syncthreads();
    const float4 av = *(const float4*)(A  + arow + kk + lc);
    const float4 wv = *(const float4*)(Tb + wrow + kk + lc);
    As[lr][lc+0]=av.x; As[lr][lc+1]=av.y; As[lr][lc+2]=av.z; As[lr][lc+3]=av.w;
    Ws[lr][lc+0]=wv.x; Ws[lr][lc+1]=wv.y; Ws[lr][lc+2]=wv.z; Ws[lr][lc+3]=wv.w;
    __syncthreads();
#pragma unroll
    for (int c = 0; c < 16; ++c) {
      float a[4], b[4];
#pragma unroll
      for (int i = 0; i < 4; ++i) a[i] = As[ty + 16*i][c];
#pragma unroll
      for (int j = 0; j < 4; ++j) b[j] = Ws[tx + 16*j][c];
#pragma unroll
      for (int i = 0; i < 4; ++i)
#pragma unroll
        for (int j = 0; j < 4; ++j) acc[i][j] = fmaf(a[i], b[j], acc[i][j]);
    }
  }
#pragma unroll
  for (int i = 0; i < 4; ++i) {
    unsigned long long best = 0ull;
#pragma unroll
    for (int j = 0; j < 4; ++j) {
      unsigned ub = __float_as_uint(acc[i][j]);
      ub = (ub & 0x80000000u) ? ~ub : (ub | 0x80000000u);  // monotone f32->u32
      const unsigned n = (unsigned)(n0 + tx + 16*j);
      const unsigned long long p =
          ((unsigned long long)ub << 32) | (unsigned long long)(0xFFFFFFFFu - n);
      best = best > p ? best : p;
    }
    // reduce across the 16 lanes (tx) that share this output row
#pragma unroll
    for (int off = 1; off < 16; off <<= 1) {
      const unsigned long long o = __shfl_xor(best, off, 64);
      best = best > o ? best : o;
    }
    if (tx == 0) atomicMax(&amax[m0 + ty + 16*i], best);
  }
}

__global__ void bikv_zero_amax(unsigned long long* a) {
  const int i = blockIdx.x * 256 + threadIdx.x;
  if (i < M_) a[i] = 0ull;
}

__global__ void bikv_decode(const unsigned long long* __restrict__ amax,
                            int* __restrict__ ch) {
  const int i = blockIdx.x * 256 + threadIdx.x;
  if (i < M_) ch[i] = (int)(0xFFFFFFFFu - (unsigned)(amax[i] & 0xFFFFFFFFull));
}

// ---------------------------------------------------------------------------
// Rotary: NOTE the reference applies cos/sin indexed by HEAD index (table
// built with n = NH), not sequence position. One thread per (m, nh, j<32) pair.
// ---------------------------------------------------------------------------
__global__ __launch_bounds__(256) void bikv_rotary(float* __restrict__ buf) {
  const int e  = blockIdx.x * 256 + threadIdx.x;   // e < M_*NH_*32 exactly
  const int j  = e & 31;
  const int nh = (e >> 5) & 7;
  const long m = e >> 8;
  const float inv = expf(-(float)j * (9.2103403719761836f / 32.0f)); // 10000^(-j/32)
  const float arg = (float)nh * inv;
  const float c = cosf(arg), s = sinf(arg);
  float* p = buf + m * H_ + nh * HD_ + j;
  const float x1 = p[0], x2 = p[32];
  p[0]  = x1 * c - x2 * s;
  p[32] = x2 * c + x1 * s;
}

// ---------------------------------------------------------------------------
// Flash attention: one wave per query row (4 queries / workgroup), K/V staged
// in LDS per 64-key tile, online softmax. scores = q.k/8 + bias, causal.
// ---------------------------------------------------------------------------
__global__ __launch_bounds__(256) void bikv_attn(
    const float* __restrict__ qb, const float* __restrict__ kb,
    const float* __restrict__ vb, const float* __restrict__ bias,
    float* __restrict__ ob)
{
  const int b = blockIdx.z, h = blockIdx.y;
  const int t = threadIdx.x, wv = t >> 6, lane = t & 63;
  const int q = blockIdx.x * 4 + wv;
  __shared__ float kt[64][65];
  __shared__ float vt[64][65];
  __shared__ float qs[4][64];
  __shared__ float wsh[4][64];
  const long qoff = (((long)(b * S_ + q)) * NH_ + h) * HD_;
  qs[wv][lane] = qb[qoff + lane];
  const float* biasrow = bias + ((long)b * S_ + q) * S_;
  const int ntiles = (blockIdx.x >> 4) + 1;   // uniform across the 4 waves
  float m = -INFINITY, l = 0.f, oacc = 0.f;
  for (int tau = 0; tau < ntiles; ++tau) {
    const int t0 = tau * 64;
    __syncthreads();
    {
      const float* ksrc = kb + (((long)(b * S_ + t0)) * NH_ + h) * HD_;
      const float* vsrc = vb + (((long)(b * S_ + t0)) * NH_ + h) * HD_;
      int l4 = t;
#pragma unroll
      for (int rep = 0; rep < 4; ++rep, l4 += 256) {
        const int row = l4 >> 4;
        const int c4  = (l4 & 15) << 2;
        const float4 kv4 = *(const float4*)(ksrc + (long)row * (NH_*HD_) + c4);
        const float4 vv4 = *(const float4*)(vsrc + (long)row * (NH_*HD_) + c4);
        kt[row][c4+0]=kv4.x; kt[row][c4+1]=kv4.y; kt[row][c4+2]=kv4.z; kt[row][c4+3]=kv4.w;
        vt[row][c4+0]=vv4.x; vt[row][c4+1]=vv4.y; vt[row][c4+2]=vv4.z; vt[row][c4+3]=vv4.w;
      }
    }
    __syncthreads();
    const int tg = t0 + lane;
    const bool valid = tg <= q;
    float dot = 0.f;
#pragma unroll
    for (int d = 0; d < 64; ++d) dot = fmaf(qs[wv][d], kt[lane][d], dot);
    const float sc = valid ? (dot * 0.125f + biasrow[tg]) : -INFINITY;
    float tm = sc;
#pragma unroll
    for (int off = 32; off >= 1; off >>= 1) tm = fmaxf(tm, __shfl_xor(tm, off, 64));
    const float mnew  = fmaxf(m, tm);            // finite: >=1 valid key per tile
    const float alpha = expf(m - mnew);          // first tile: exp(-inf) = 0
    const float w = valid ? expf(sc - mnew) : 0.f;
    float sw = w;
#pragma unroll
    for (int off = 32; off >= 1; off >>= 1) sw += __shfl_xor(sw, off, 64);
    l = l * alpha + sw;
    wsh[wv][lane] = w;
    __syncthreads();
    float pa = 0.f;
#pragma unroll
    for (int tt = 0; tt < 64; ++tt) pa = fmaf(wsh[wv][tt], vt[tt][lane], pa);
    oacc = oacc * alpha + pa;
    m = mnew;
  }
  ob[qoff + lane] = oacc / l;
}

// ---------------------------------------------------------------------------
extern "C" void kernel_launch(void* const* d_in, const int* in_sizes, int n_in,
                              void* d_out, int out_size, void* d_ws, size_t ws_size,
                              hipStream_t stream)
{
  const float* X     = (const float*)d_in[0];   // [B,S,H]
  const float* i_w   = (const float*)d_in[1];   // [I,H]
  const float* q_w   = (const float*)d_in[2];   // [H,H]
  const float* k_w   = (const float*)d_in[3];
  const float* v_w   = (const float*)d_in[4];
  const float* out_w = (const float*)d_in[5];
  const float* out_b = (const float*)d_in[6];   // [H]
  const float* tab   = (const float*)d_in[7];   // [K,I]
  const float* ktab  = (const float*)d_in[8];   // [K,H]
  const float* vtab  = (const float*)d_in[9];   // [K,H]
  float* out = (float*)d_out;

  char* ws = (char*)d_ws;
  size_t off = 0;
  auto alloc = [&](size_t bytes) -> void* {
    void* p = ws + off; off += (bytes + 255) & ~(size_t)255; return p;
  };
  auto amax    = (unsigned long long*)alloc(M_ * 8);
  auto choices = (int*)  alloc(M_ * 4);
  auto idxb    = (float*)alloc((size_t)M_ * I_ * 4);
  auto chosenb = (float*)alloc((size_t)M_ * I_ * 4);
  auto qbuf    = (float*)alloc((size_t)M_ * H_ * 4);
  auto kbuf    = (float*)alloc((size_t)M_ * H_ * 4);
  auto vbuf    = (float*)alloc((size_t)M_ * H_ * 4);
  auto obuf    = (float*)alloc((size_t)M_ * H_ * 4);
  auto biasb   = (float*)alloc((size_t)B_ * S_ * S_ * 4);  // total ~33.6 MB

  // amax buffer is re-poisoned 0xAA each timed call -> re-zero every launch
  bikv_zero_amax<<<M_/256, 256, 0, stream>>>(amax);

  // idx = sigmoid(X . i_w^T)
  bikv_gemm_bt<true,false,false><<<dim3(M_/64, I_/64), 256, 0, stream>>>(
      X, i_w, idxb, nullptr, nullptr, I_, H_, 0, 0, 0);

  // fused sim GEMM + argmax over 65536 codebook entries
  bikv_sim_argmax<<<dim3(M_/64, K_/64), 256, 0, stream>>>(idxb, tab, amax);
  bikv_decode<<<M_/256, 256, 0, stream>>>(amax, choices);

  // cached[choices] = sigmoid(tab[choice] . i_w^T)  (only 2048 rows, not 65536)
  bikv_gemm_bt<true,true,false><<<dim3(M_/64, I_/64), 256, 0, stream>>>(
      tab, i_w, chosenb, choices, nullptr, I_, I_, 0, 0, 0);

  // q/k/v projections (k,v gather their input rows from the big tables)
  bikv_gemm_bt<false,false,false><<<dim3(M_/64, H_/64), 256, 0, stream>>>(
      X, q_w, qbuf, nullptr, nullptr, H_, H_, 0, 0, 0);
  bikv_gemm_bt<false,true,false><<<dim3(M_/64, H_/64), 256, 0, stream>>>(
      ktab, k_w, kbuf, choices, nullptr, H_, H_, 0, 0, 0);
  bikv_gemm_bt<false,true,false><<<dim3(M_/64, H_/64), 256, 0, stream>>>(
      vtab, v_w, vbuf, choices, nullptr, H_, H_, 0, 0, 0);

  bikv_rotary<<<(M_*NH_*32)/256, 256, 0, stream>>>(qbuf);
  bikv_rotary<<<(M_*NH_*32)/256, 256, 0, stream>>>(kbuf);

  // bias[b,s,t] = idx[b,s,:] . chosen[b,t,:]
  bikv_gemm_bt<false,false,false><<<dim3(S_/64, S_/64, B_), 256, 0, stream>>>(
      idxb, chosenb, biasb, nullptr, nullptr, S_, I_,
      (long)S_ * I_, (long)S_ * I_, (long)S_ * S_);

  bikv_attn<<<dim3(S_/4, NH_, B_), 256, 0, stream>>>(qbuf, kbuf, vbuf, biasb, obuf);

  // out = o . out_w^T + out_b
  bikv_gemm_bt<false,false,true><<<dim3(M_/64, H_/64), 256, 0, stream>>>(
      obuf, out_w, out, nullptr, out_b, H_, H_, 0, 0, 0);
}

// Round 2
// 1180.851 us; speedup vs baseline: 2.5682x; 2.5682x over previous
//
#include <hip/hip_runtime.h>
#include <cmath>

namespace {
constexpr int B_  = 2;
constexpr int S_  = 1024;
constexpr int H_  = 512;
constexpr int NH_ = 8;
constexpr int HD_ = 64;
constexpr int I_  = 512;
constexpr int K_  = 65536;
constexpr int M_  = B_ * S_;   // 2048
constexpr int CAP = 1024;      // candidate slots per row
}

typedef __attribute__((ext_vector_type(8))) short short8;
typedef __attribute__((ext_vector_type(4))) float f32x4;

__device__ inline unsigned mono(float f) {
  unsigned u = __float_as_uint(f);
  return (u & 0x80000000u) ? ~u : (u | 0x80000000u);
}
__device__ inline float unmono(unsigned m) {
  unsigned u = (m & 0x80000000u) ? (m & 0x7fffffffu) : ~m;
  return __uint_as_float(u);
}
__device__ inline unsigned short f2bf(float f) {      // RNE f32 -> bf16
  unsigned u = __float_as_uint(f);
  return (unsigned short)((u + 0x7fffu + ((u >> 16) & 1u)) >> 16);
}

// ---------------------------------------------------------------------------
// Generic fp32 GEMM, B-transposed: C[m,n] = act(sum_k A[row(m),k] * W[n,k])
// ---------------------------------------------------------------------------
template<bool SIG, bool GATH, bool BVEC>
__global__ __launch_bounds__(256) void bikv_gemm_bt(
    const float* __restrict__ A, const float* __restrict__ W,
    float* __restrict__ C, const int* __restrict__ gidx,
    const float* __restrict__ bvec, int N, int Kd,
    long sA, long sW, long sC)
{
  A += (long)blockIdx.z * sA;
  W += (long)blockIdx.z * sW;
  C += (long)blockIdx.z * sC;
  __shared__ float As[64][17];
  __shared__ float Ws[64][17];
  const int t  = threadIdx.x;
  const int m0 = blockIdx.x * 64;
  const int n0 = blockIdx.y * 64;
  const int ty = t >> 4, tx = t & 15;
  const int lr = t >> 2, lc = (t & 3) << 2;
  long arow;
  if (GATH) arow = (long)gidx[m0 + lr] * Kd;
  else      arow = (long)(m0 + lr) * Kd;
  const long wrow = (long)(n0 + lr) * Kd;
  float acc[4][4] = {};
  for (int kk = 0; kk < Kd; kk += 16) {
    __syncthreads();
    const float4 av = *(const float4*)(A + arow + kk + lc);
    const float4 wv = *(const float4*)(W + wrow + kk + lc);
    As[lr][lc+0]=av.x; As[lr][lc+1]=av.y; As[lr][lc+2]=av.z; As[lr][lc+3]=av.w;
    Ws[lr][lc+0]=wv.x; Ws[lr][lc+1]=wv.y; Ws[lr][lc+2]=wv.z; Ws[lr][lc+3]=wv.w;
    __syncthreads();
#pragma unroll
    for (int c = 0; c < 16; ++c) {
      float a[4], b[4];
#pragma unroll
      for (int i = 0; i < 4; ++i) a[i] = As[ty + 16*i][c];
#pragma unroll
      for (int j = 0; j < 4; ++j) b[j] = Ws[tx + 16*j][c];
#pragma unroll
      for (int i = 0; i < 4; ++i)
#pragma unroll
        for (int j = 0; j < 4; ++j) acc[i][j] = fmaf(a[i], b[j], acc[i][j]);
    }
  }
#pragma unroll
  for (int i = 0; i < 4; ++i) {
    const long m = m0 + ty + 16*i;
#pragma unroll
    for (int j = 0; j < 4; ++j) {
      const int n = n0 + tx + 16*j;
      float v = acc[i][j];
      if (BVEC) v += bvec[n];
      if (SIG)  v = 1.0f / (1.0f + expf(-v));
      C[m * N + n] = v;
    }
  }
}

// ---------------------------------------------------------------------------
// f32 -> bf16 conversion, 8 elems/thread
// ---------------------------------------------------------------------------
__global__ __launch_bounds__(256) void bikv_f2bf(
    const float* __restrict__ src, unsigned short* __restrict__ dst, int n8)
{
  const int i = blockIdx.x * 256 + threadIdx.x;
  if (i >= n8) return;
  const float4 x = *(const float4*)(src + (long)i * 8);
  const float4 y = *(const float4*)(src + (long)i * 8 + 4);
  uint4 o;
  o.x = ((unsigned)f2bf(x.y) << 16) | f2bf(x.x);
  o.y = ((unsigned)f2bf(x.w) << 16) | f2bf(x.z);
  o.z = ((unsigned)f2bf(y.y) << 16) | f2bf(y.x);
  o.w = ((unsigned)f2bf(y.w) << 16) | f2bf(y.z);
  *(uint4*)(dst + (long)i * 8) = o;
}

__global__ void bikv_zero(unsigned long long* a, int* cc) {
  const int i = blockIdx.x * 256 + threadIdx.x;
  if (i < M_) { a[i] = 0ull; cc[i] = 0; }
}

// ---------------------------------------------------------------------------
// MFMA sim = idx . tab^T (bf16 inputs, fp32 acc), fused approx-argmax +
// candidate collection. 128x128 tile, 4 waves (2x2 of 64x64), 16x16x32 MFMA,
// global_load_lds width-16 staging. Packed key = (monotone_f32<<32) | ~col.
// Any entry within MARGIN of max(block-local, global-so-far) max is recorded;
// the true argmax is provably always in the candidate list (MARGIN >> 2*err).
// ---------------------------------------------------------------------------
__global__ __launch_bounds__(256) void bikv_sim_mfma(
    const unsigned short* __restrict__ A,    // idx bf16 [M_, I_]
    const unsigned short* __restrict__ Tb,   // tab bf16 [K_, I_]
    unsigned long long* __restrict__ amax,
    int* __restrict__ ccount,
    unsigned long long* __restrict__ cand)
{
  constexpr float MARGIN = 1.0f;
  __shared__ unsigned short As[128 * 32];
  __shared__ unsigned short Bs[128 * 32];
  const int t = threadIdx.x;
  const int w = t >> 6, l = t & 63;
  const int q = l >> 4, c = l & 15;
  const int wm = w >> 1, wn = w & 1;
  const int m0 = blockIdx.x * 128;
  const int n0 = blockIdx.y * 128;

  f32x4 acc[4][4];
#pragma unroll
  for (int i = 0; i < 4; ++i)
#pragma unroll
    for (int j = 0; j < 4; ++j) acc[i][j] = (f32x4)0.0f;

  for (int kk = 0; kk < I_; kk += 32) {
    __syncthreads();
#pragma unroll
    for (int rep = 0; rep < 2; ++rep) {
      const int s   = rep * 256 + w * 64 + l;
      const int row = s >> 2, cp = s & 3;
      const long ga = (long)(m0 + row) * I_ + kk + cp * 8;
      const long gb = (long)(n0 + row) * I_ + kk + cp * 8;
      const int lbase = (rep * 256 + w * 64) * 16;  // bytes, wave-uniform
      __builtin_amdgcn_global_load_lds(
          (const __attribute__((address_space(1))) void*)(A + ga),
          (__attribute__((address_space(3))) void*)((char*)As + lbase), 16, 0, 0);
      __builtin_amdgcn_global_load_lds(
          (const __attribute__((address_space(1))) void*)(Tb + gb),
          (__attribute__((address_space(3))) void*)((char*)Bs + lbase), 16, 0, 0);
    }
    __syncthreads();

    short8 af[4], bfr[4];
#pragma unroll
    for (int i = 0; i < 4; ++i) {
      af[i]  = *(const short8*)(As + (wm * 64 + i * 16 + c) * 32 + q * 8);
      bfr[i] = *(const short8*)(Bs + (wn * 64 + i * 16 + c) * 32 + q * 8);
    }
#pragma unroll
    for (int i = 0; i < 4; ++i)
#pragma unroll
      for (int j = 0; j < 4; ++j)
        acc[i][j] = __builtin_amdgcn_mfma_f32_16x16x32_bf16(af[i], bfr[j], acc[i][j], 0, 0, 0);
  }

  // Epilogue: C/D layout col = lane&15, row = (lane>>4)*4 + reg [m89/m91]
#pragma unroll
  for (int i = 0; i < 4; ++i) {
#pragma unroll
    for (int r = 0; r < 4; ++r) {
      const int mrow = m0 + wm * 64 + i * 16 + q * 4 + r;
      unsigned long long best = 0ull;
#pragma unroll
      for (int j = 0; j < 4; ++j) {
        const float v = acc[i][j][r];
        const unsigned n = (unsigned)(n0 + wn * 64 + j * 16 + c);
        const unsigned long long p =
            ((unsigned long long)mono(v) << 32) | (unsigned long long)(0xFFFFFFFFu - n);
        best = best > p ? best : p;
      }
#pragma unroll
      for (int off = 1; off < 16; off <<= 1) {   // reduce within quad (same row)
        const unsigned long long o = __shfl_xor(best, off, 64);
        best = best > o ? best : o;
      }
      unsigned long long known = best;
      if (c == 0) {
        const unsigned long long old = atomicMax(&amax[mrow], best);
        known = old > best ? old : best;
      }
      known = __shfl(known, q * 16, 64);
      const float thr = unmono((unsigned)(known >> 32)) - MARGIN;
#pragma unroll
      for (int j = 0; j < 4; ++j) {
        const float v = acc[i][j][r];
        if (v > thr) {
          const unsigned n = (unsigned)(n0 + wn * 64 + j * 16 + c);
          const unsigned long long p =
              ((unsigned long long)mono(v) << 32) | (unsigned long long)(0xFFFFFFFFu - n);
          const int pos = atomicAdd(&ccount[mrow], 1);
          if (pos < CAP) cand[(long)mrow * CAP + pos] = p;
        }
      }
    }
  }
}

// ---------------------------------------------------------------------------
// Exact fp32 rescore of candidates within MARGIN of the final approx max.
// One wave per row. Numpy argmax tie-break via packed ~col.
// ---------------------------------------------------------------------------
__global__ __launch_bounds__(256) void bikv_rescore(
    const float* __restrict__ idxb, const float* __restrict__ tab,
    const unsigned long long* __restrict__ amax,
    const int* __restrict__ ccount, const unsigned long long* __restrict__ cand,
    int* __restrict__ ch)
{
  constexpr float MARGIN = 1.0f;
  const int t = threadIdx.x, wv = t >> 6, l = t & 63;
  const int m = blockIdx.x * 4 + wv;
  float a[8];
  {
    const float4 a0 = *(const float4*)(idxb + (long)m * I_ + l * 8);
    const float4 a1 = *(const float4*)(idxb + (long)m * I_ + l * 8 + 4);
    a[0]=a0.x; a[1]=a0.y; a[2]=a0.z; a[3]=a0.w;
    a[4]=a1.x; a[5]=a1.y; a[6]=a1.z; a[7]=a1.w;
  }
  const int count = min(ccount[m], CAP);
  const float thrv = unmono((unsigned)(amax[m] >> 32)) - MARGIN;
  unsigned long long best = 0ull;
  for (int cix = 0; cix < count; ++cix) {
    const unsigned long long p = cand[(long)m * CAP + cix];
    if (unmono((unsigned)(p >> 32)) <= thrv) continue;
    const unsigned col = 0xFFFFFFFFu - (unsigned)(p & 0xFFFFFFFFull);
    const float* tr = tab + (long)col * I_ + l * 8;
    float s = 0.f;
#pragma unroll
    for (int j = 0; j < 8; ++j) s = fmaf(a[j], tr[j], s);
#pragma unroll
    for (int off = 32; off >= 1; off >>= 1) s += __shfl_xor(s, off, 64);
    const unsigned long long pe =
        ((unsigned long long)mono(s) << 32) | (unsigned long long)(0xFFFFFFFFu - col);
    best = best > pe ? best : pe;
  }
  if (l == 0) ch[m] = (int)(0xFFFFFFFFu - (unsigned)(best & 0xFFFFFFFFull));
}

// ---------------------------------------------------------------------------
// Rotary (cos/sin indexed by HEAD index — reference quirk)
// ---------------------------------------------------------------------------
__global__ __launch_bounds__(256) void bikv_rotary(float* __restrict__ buf) {
  const int e  = blockIdx.x * 256 + threadIdx.x;
  const int j  = e & 31;
  const int nh = (e >> 5) & 7;
  const long m = e >> 8;
  const float inv = expf(-(float)j * (9.2103403719761836f / 32.0f));
  const float arg = (float)nh * inv;
  const float c = cosf(arg), s = sinf(arg);
  float* p = buf + m * H_ + nh * HD_ + j;
  const float x1 = p[0], x2 = p[32];
  p[0]  = x1 * c - x2 * s;
  p[32] = x2 * c + x1 * s;
}

// ---------------------------------------------------------------------------
// Flash attention: one wave per query row, K/V staged in LDS per 64-key tile.
// ---------------------------------------------------------------------------
__global__ __launch_bounds__(256) void bikv_attn(
    const float* __restrict__ qb, const float* __restrict__ kb,
    const float* __restrict__ vb, const float* __restrict__ bias,
    float* __restrict__ ob)
{
  const int b = blockIdx.z, h = blockIdx.y;
  const int t = threadIdx.x, wv = t >> 6, lane = t & 63;
  const int q = blockIdx.x * 4 + wv;
  __shared__ float kt[64][65];
  __shared__ float vt[64][65];
  __shared__ float qs[4][64];
  __shared__ float wsh[4][64];
  const long qoff = (((long)(b * S_ + q)) * NH_ + h) * HD_;
  qs[wv][lane] = qb[qoff + lane];
  const float* biasrow = bias + ((long)b * S_ + q) * S_;
  const int ntiles = (blockIdx.x >> 4) + 1;
  float m = -INFINITY, l = 0.f, oacc = 0.f;
  for (int tau = 0; tau < ntiles; ++tau) {
    const int t0 = tau * 64;
    __syncthreads();
    {
      const float* ksrc = kb + (((long)(b * S_ + t0)) * NH_ + h) * HD_;
      const float* vsrc = vb + (((long)(b * S_ + t0)) * NH_ + h) * HD_;
      int l4 = t;
#pragma unroll
      for (int rep = 0; rep < 4; ++rep, l4 += 256) {
        const int row = l4 >> 4;
        const int c4  = (l4 & 15) << 2;
        const float4 kv4 = *(const float4*)(ksrc + (long)row * (NH_*HD_) + c4);
        const float4 vv4 = *(const float4*)(vsrc + (long)row * (NH_*HD_) + c4);
        kt[row][c4+0]=kv4.x; kt[row][c4+1]=kv4.y; kt[row][c4+2]=kv4.z; kt[row][c4+3]=kv4.w;
        vt[row][c4+0]=vv4.x; vt[row][c4+1]=vv4.y; vt[row][c4+2]=vv4.z; vt[row][c4+3]=vv4.w;
      }
    }
    __syncthreads();
    const int tg = t0 + lane;
    const bool valid = tg <= q;
    float dot = 0.f;
#pragma unroll
    for (int d = 0; d < 64; ++d) dot = fmaf(qs[wv][d], kt[lane][d], dot);
    const float sc = valid ? (dot * 0.125f + biasrow[tg]) : -INFINITY;
    float tm = sc;
#pragma unroll
    for (int off = 32; off >= 1; off >>= 1) tm = fmaxf(tm, __shfl_xor(tm, off, 64));
    const float mnew  = fmaxf(m, tm);
    const float alpha = expf(m - mnew);
    const float w = valid ? expf(sc - mnew) : 0.f;
    float sw = w;
#pragma unroll
    for (int off = 32; off >= 1; off >>= 1) sw += __shfl_xor(sw, off, 64);
    l = l * alpha + sw;
    wsh[wv][lane] = w;
    __syncthreads();
    float pa = 0.f;
#pragma unroll
    for (int tt = 0; tt < 64; ++tt) pa = fmaf(wsh[wv][tt], vt[tt][lane], pa);
    oacc = oacc * alpha + pa;
    m = mnew;
  }
  ob[qoff + lane] = oacc / l;
}

// ---------------------------------------------------------------------------
extern "C" void kernel_launch(void* const* d_in, const int* in_sizes, int n_in,
                              void* d_out, int out_size, void* d_ws, size_t ws_size,
                              hipStream_t stream)
{
  const float* X     = (const float*)d_in[0];
  const float* i_w   = (const float*)d_in[1];
  const float* q_w   = (const float*)d_in[2];
  const float* k_w   = (const float*)d_in[3];
  const float* v_w   = (const float*)d_in[4];
  const float* out_w = (const float*)d_in[5];
  const float* out_b = (const float*)d_in[6];
  const float* tab   = (const float*)d_in[7];
  const float* ktab  = (const float*)d_in[8];
  const float* vtab  = (const float*)d_in[9];
  float* out = (float*)d_out;

  char* ws = (char*)d_ws;
  size_t off = 0;
  auto alloc = [&](size_t bytes) -> void* {
    void* p = ws + off; off += (bytes + 255) & ~(size_t)255; return p;
  };
  auto amax    = (unsigned long long*)alloc(M_ * 8);
  auto ccount  = (int*)  alloc(M_ * 4);
  auto choices = (int*)  alloc(M_ * 4);
  auto idxb    = (float*)alloc((size_t)M_ * I_ * 4);
  auto chosenb = (float*)alloc((size_t)M_ * I_ * 4);
  auto qbuf    = (float*)alloc((size_t)M_ * H_ * 4);
  auto kbuf    = (float*)alloc((size_t)M_ * H_ * 4);
  auto vbuf    = (float*)alloc((size_t)M_ * H_ * 4);
  auto obuf    = (float*)alloc((size_t)M_ * H_ * 4);
  auto biasb   = (float*)alloc((size_t)B_ * S_ * S_ * 4);
  auto idx16   = (unsigned short*)alloc((size_t)M_ * I_ * 2);
  auto tab16   = (unsigned short*)alloc((size_t)K_ * I_ * 2);   // 67 MB
  auto cand    = (unsigned long long*)alloc((size_t)M_ * CAP * 8);  // 16.8 MB

  // ws is re-poisoned before every timed call -> re-init every launch
  bikv_zero<<<M_/256, 256, 0, stream>>>(amax, ccount);

  // tab -> bf16 (independent of idx computation)
  bikv_f2bf<<<(K_*I_/8 + 255)/256, 256, 0, stream>>>(tab, tab16, K_*I_/8);

  // idx = sigmoid(X . i_w^T)
  bikv_gemm_bt<true,false,false><<<dim3(M_/64, I_/64), 256, 0, stream>>>(
      X, i_w, idxb, nullptr, nullptr, I_, H_, 0, 0, 0);
  bikv_f2bf<<<(M_*I_/8 + 255)/256, 256, 0, stream>>>(idxb, idx16, M_*I_/8);

  // MFMA sim + approx argmax + candidates; then exact fp32 rescore
  bikv_sim_mfma<<<dim3(M_/128, K_/128), 256, 0, stream>>>(
      idx16, tab16, amax, ccount, cand);
  bikv_rescore<<<M_/4, 256, 0, stream>>>(idxb, tab, amax, ccount, cand, choices);

  // cached[choices] = sigmoid(tab[choice] . i_w^T)
  bikv_gemm_bt<true,true,false><<<dim3(M_/64, I_/64), 256, 0, stream>>>(
      tab, i_w, chosenb, choices, nullptr, I_, I_, 0, 0, 0);

  // q/k/v projections
  bikv_gemm_bt<false,false,false><<<dim3(M_/64, H_/64), 256, 0, stream>>>(
      X, q_w, qbuf, nullptr, nullptr, H_, H_, 0, 0, 0);
  bikv_gemm_bt<false,true,false><<<dim3(M_/64, H_/64), 256, 0, stream>>>(
      ktab, k_w, kbuf, choices, nullptr, H_, H_, 0, 0, 0);
  bikv_gemm_bt<false,true,false><<<dim3(M_/64, H_/64), 256, 0, stream>>>(
      vtab, v_w, vbuf, choices, nullptr, H_, H_, 0, 0, 0);

  bikv_rotary<<<(M_*NH_*32)/256, 256, 0, stream>>>(qbuf);
  bikv_rotary<<<(M_*NH_*32)/256, 256, 0, stream>>>(kbuf);

  // bias[b,s,t] = idx[b,s,:] . chosen[b,t,:]  (fp32: feeds softmax exponent)
  bikv_gemm_bt<false,false,false><<<dim3(S_/64, S_/64, B_), 256, 0, stream>>>(
      idxb, chosenb, biasb, nullptr, nullptr, S_, I_,
      (long)S_ * I_, (long)S_ * I_, (long)S_ * S_);

  bikv_attn<<<dim3(S_/4, NH_, B_), 256, 0, stream>>>(qbuf, kbuf, vbuf, biasb, obuf);

  // out = o . out_w^T + out_b
  bikv_gemm_bt<false,false,true><<<dim3(M_/64, H_/64), 256, 0, stream>>>(
      obuf, out_w, out, nullptr, out_b, H_, H_, 0, 0, 0);
}